// Round 5
// baseline (448.521 us; speedup 1.0000x reference)
//
#include <hip/hip_runtime.h>
#include <hip/hip_cooperative_groups.h>

namespace cg = cooperative_groups;

#define NN 2048
#define FF 128
#define SLOPE 0.1f
#define XS_STRIDE 136           // padded bf16 row stride in LDS

typedef __attribute__((ext_vector_type(8))) short short8;
typedef __attribute__((ext_vector_type(4))) float f32x4;

__device__ __forceinline__ float lrelu(float v) { return v >= 0.f ? v : SLOPE * v; }

__device__ __forceinline__ ushort f2bf(float f) {
    uint u = __float_as_uint(f);
    return (ushort)((u + 0x7fffu + ((u >> 16) & 1u)) >> 16);
}

// ===========================================================================
// Shared 32-row helpers (fallback path, proven in round 3)
// ===========================================================================

__device__ __forceinline__ void mfma_AB(
    const ushort* __restrict__ As, const ushort* __restrict__ Bg,
    int c, int quad, int ct0, f32x4 acc[2][2])
{
#pragma unroll
    for (int kk = 0; kk < 4; kk++) {
        short8 a0 = *(const short8*)&As[c * XS_STRIDE + kk * 32 + quad * 8];
        short8 a1 = *(const short8*)&As[(16 + c) * XS_STRIDE + kk * 32 + quad * 8];
#pragma unroll
        for (int ct = 0; ct < 2; ct++) {
            const int n = (ct0 + ct) * 16 + c;
            short8 bf = *(const short8*)&Bg[n * 128 + kk * 32 + quad * 8];
            acc[0][ct] = __builtin_amdgcn_mfma_f32_16x16x32_bf16(a0, bf, acc[0][ct], 0, 0, 0);
            acc[1][ct] = __builtin_amdgcn_mfma_f32_16x16x32_bf16(a1, bf, acc[1][ct], 0, 0, 0);
        }
    }
}

__device__ __forceinline__ void write_xt32(
    const ushort* __restrict__ s, ushort* __restrict__ xt,
    int tid, int b, int jloc0)
{
    const int g = tid >> 1;
    const int h = tid & 1;
    uint p[8];
#pragma unroll
    for (int jj = 0; jj < 8; jj++) {
        const uint lo = s[(h * 16 + jj * 2) * XS_STRIDE + g];
        const uint hi = s[(h * 16 + jj * 2 + 1) * XS_STRIDE + g];
        p[jj] = lo | (hi << 16);
    }
    uint4* dst = (uint4*)&xt[(size_t)b * (FF * NN) + (size_t)g * NN + jloc0 + h * 16];
    dst[0] = make_uint4(p[0], p[1], p[2], p[3]);
    dst[1] = make_uint4(p[4], p[5], p[6], p[7]);
}

__device__ __forceinline__ void w12_epilogue32(
    const f32x4 acc1[2][2], const f32x4 acc2[2][2],
    const float* __restrict__ b3, const float* __restrict__ b4,
    ushort* __restrict__ w1dst, ushort* __restrict__ w2t, float* __restrict__ diag_s,
    int b, int jloc0, int c, int quad, int ct0)
{
    float dpar[2][4];
#pragma unroll
    for (int rt = 0; rt < 2; rt++)
#pragma unroll
        for (int r = 0; r < 4; r++) dpar[rt][r] = 0.f;

#pragma unroll
    for (int rt = 0; rt < 2; rt++) {
#pragma unroll
        for (int ct = 0; ct < 2; ct++) {
            const int gcol = (ct0 + ct) * 16 + c;
            const float bb3 = b3[gcol], bb4 = b4[gcol];
            ushort w2p[4];
#pragma unroll
            for (int r = 0; r < 4; r++) {
                const float v1 = lrelu(acc1[rt][ct][r] + bb3);
                const float v2 = lrelu(acc2[rt][ct][r] + bb4);
                const int lrow = rt * 16 + quad * 4 + r;
                w1dst[lrow * XS_STRIDE + gcol] = f2bf(v1);
                w2p[r] = f2bf(v2);
                dpar[rt][r] += v1 * v2;
            }
            const uint lo = (uint)w2p[0] | ((uint)w2p[1] << 16);
            const uint hi = (uint)w2p[2] | ((uint)w2p[3] << 16);
            *(uint2*)&w2t[(size_t)b * (FF * NN) + (size_t)gcol * NN +
                          jloc0 + rt * 16 + quad * 4] = make_uint2(lo, hi);
        }
    }
#pragma unroll
    for (int rt = 0; rt < 2; rt++) {
#pragma unroll
        for (int r = 0; r < 4; r++) {
            float dp = dpar[rt][r];
            dp += __shfl_xor(dp, 1, 64);
            dp += __shfl_xor(dp, 2, 64);
            dp += __shfl_xor(dp, 4, 64);
            dp += __shfl_xor(dp, 8, 64);
            if (c == 0) atomicAdd(&diag_s[rt * 16 + quad * 4 + r], dp);
        }
    }
}

// S phase for 256 blocks (round-3 k_S2 body)
__device__ __forceinline__ void s_phase256(
    const ushort* __restrict__ xt, const ushort* __restrict__ w2t,
    ushort* __restrict__ St, float (*red)[512],
    int blk, int tid, int wave, int c, int quad)
{
    const int sb = blk >> 5;          // batch
    const int gq = (blk >> 3) & 3;    // 32-g quarter
    const int fs = blk & 7;           // 16-f strip

    const int j0 = wave * 512 + quad * 8;
    const ushort* a0p = &xt[(size_t)sb * (FF * NN) + (size_t)(gq * 32 + c) * NN + j0];
    const ushort* a1p = &xt[(size_t)sb * (FF * NN) + (size_t)(gq * 32 + 16 + c) * NN + j0];
    const ushort* bp  = &w2t[(size_t)sb * (FF * NN) + (size_t)(fs * 16 + c) * NN + j0];

    f32x4 acc0 = (f32x4)0.f, acc1 = (f32x4)0.f;
#pragma unroll
    for (int it = 0; it < 16; it++) {
        short8 a0 = *(const short8*)(a0p + it * 32);
        short8 a1 = *(const short8*)(a1p + it * 32);
        short8 bf = *(const short8*)(bp + it * 32);
        acc0 = __builtin_amdgcn_mfma_f32_16x16x32_bf16(a0, bf, acc0, 0, 0, 0);
        acc1 = __builtin_amdgcn_mfma_f32_16x16x32_bf16(a1, bf, acc1, 0, 0, 0);
    }
#pragma unroll
    for (int r = 0; r < 4; r++) {
        red[wave][(quad * 4 + r) * 16 + c] = acc0[r];
        red[wave][(16 + quad * 4 + r) * 16 + c] = acc1[r];
    }
    __syncthreads();
#pragma unroll
    for (int i = 0; i < 2; i++) {
        const int idx = i * 256 + tid;
        const float s = red[0][idx] + red[1][idx] + red[2][idx] + red[3][idx];
        const int gl = idx >> 4, fl = idx & 15;
        St[(size_t)sb * (FF * FF) + (size_t)(gq * 32 + gl) * FF + fs * 16 + fl] = f2bf(s);
    }
}

// ===========================================================================
// 64-row helpers (cooperative mega-kernel)
// ===========================================================================

__device__ __forceinline__ void mfma_AB64(
    const ushort* __restrict__ As, const ushort* __restrict__ Bg,
    int c, int quad, int ct0, f32x4 acc[4][2])
{
#pragma unroll
    for (int kk = 0; kk < 4; kk++) {
        short8 a[4];
#pragma unroll
        for (int rt = 0; rt < 4; rt++)
            a[rt] = *(const short8*)&As[(rt * 16 + c) * XS_STRIDE + kk * 32 + quad * 8];
#pragma unroll
        for (int ct = 0; ct < 2; ct++) {
            const int n = (ct0 + ct) * 16 + c;
            short8 bf = *(const short8*)&Bg[n * 128 + kk * 32 + quad * 8];
#pragma unroll
            for (int rt = 0; rt < 4; rt++)
                acc[rt][ct] = __builtin_amdgcn_mfma_f32_16x16x32_bf16(a[rt], bf, acc[rt][ct], 0, 0, 0);
        }
    }
}

__device__ __forceinline__ void write_xt64(
    const ushort* __restrict__ s, ushort* __restrict__ xt,
    int tid, int b, int jloc0)
{
    const int g = tid >> 1;
    const int h = tid & 1;
    uint p[16];
#pragma unroll
    for (int jj = 0; jj < 16; jj++) {
        const uint lo = s[(h * 32 + jj * 2) * XS_STRIDE + g];
        const uint hi = s[(h * 32 + jj * 2 + 1) * XS_STRIDE + g];
        p[jj] = lo | (hi << 16);
    }
    uint4* dst = (uint4*)&xt[(size_t)b * (FF * NN) + (size_t)g * NN + jloc0 + h * 32];
    dst[0] = make_uint4(p[0], p[1], p[2], p[3]);
    dst[1] = make_uint4(p[4], p[5], p[6], p[7]);
    dst[2] = make_uint4(p[8], p[9], p[10], p[11]);
    dst[3] = make_uint4(p[12], p[13], p[14], p[15]);
}

__device__ __forceinline__ void w12_epilogue64(
    const f32x4 acc1[4][2], const f32x4 acc2[4][2],
    const float* __restrict__ b3, const float* __restrict__ b4,
    ushort* __restrict__ w1dst, ushort* __restrict__ w2t, float* __restrict__ diag_s,
    int b, int jloc0, int c, int quad, int ct0)
{
    float dpar[4][4];
#pragma unroll
    for (int rt = 0; rt < 4; rt++)
#pragma unroll
        for (int r = 0; r < 4; r++) dpar[rt][r] = 0.f;

#pragma unroll
    for (int rt = 0; rt < 4; rt++) {
#pragma unroll
        for (int ct = 0; ct < 2; ct++) {
            const int gcol = (ct0 + ct) * 16 + c;
            const float bb3 = b3[gcol], bb4 = b4[gcol];
            ushort w2p[4];
#pragma unroll
            for (int r = 0; r < 4; r++) {
                const float v1 = lrelu(acc1[rt][ct][r] + bb3);
                const float v2 = lrelu(acc2[rt][ct][r] + bb4);
                const int lrow = rt * 16 + quad * 4 + r;
                w1dst[lrow * XS_STRIDE + gcol] = f2bf(v1);
                w2p[r] = f2bf(v2);
                dpar[rt][r] += v1 * v2;
            }
            const uint lo = (uint)w2p[0] | ((uint)w2p[1] << 16);
            const uint hi = (uint)w2p[2] | ((uint)w2p[3] << 16);
            *(uint2*)&w2t[(size_t)b * (FF * NN) + (size_t)gcol * NN +
                          jloc0 + rt * 16 + quad * 4] = make_uint2(lo, hi);
        }
    }
#pragma unroll
    for (int rt = 0; rt < 4; rt++) {
#pragma unroll
        for (int r = 0; r < 4; r++) {
            float dp = dpar[rt][r];
            dp += __shfl_xor(dp, 1, 64);
            dp += __shfl_xor(dp, 2, 64);
            dp += __shfl_xor(dp, 4, 64);
            dp += __shfl_xor(dp, 8, 64);
            if (c == 0) atomicAdd(&diag_s[rt * 16 + quad * 4 + r], dp);
        }
    }
}

// ===========================================================================
// Cooperative mega-kernel: 256 blocks x 256 threads, 64 rows/block
// ===========================================================================
__global__ __launch_bounds__(256, 2) void k_all(
    const float* __restrict__ x,
    const float* __restrict__ W3, const float* __restrict__ b3,
    const float* __restrict__ W4, const float* __restrict__ b4,
    const float* __restrict__ W5, const float* __restrict__ b5,
    float* __restrict__ out,
    ushort* __restrict__ w2t, ushort* __restrict__ xt,
    ushort* __restrict__ St, ushort* __restrict__ Wt)
{
    cg::grid_group grid = cg::this_grid();

    __shared__ ushort sW[64 * XS_STRIDE];   // 17408 B
    __shared__ ushort sT[64 * XS_STRIDE];   // 17408 B
    __shared__ float red[4][512];           // 8192 B
    __shared__ float diag_s[64];

    const int tid = threadIdx.x;
    const int blk = blockIdx.x;
    const int lane = tid & 63;
    const int wave = tid >> 6;
    const int c = lane & 15;
    const int quad = lane >> 4;
    const int ct0 = wave * 2;

    const int row0 = blk * 64;
    const int b = blk >> 5;
    const int jloc0 = row0 & 2047;
    const float inv = 1.f / (float)(NN - 1);

    // ---- prep: bf16 weight transpose (all blocks participate) ----
    for (int idx = blk * 256 + tid; idx < 6 * 16384; idx += 65536) {
        const int rem = idx & 16383;
        const int f = rem & 127, g = rem >> 7;
        const int m = idx >> 14;
        const int l = m / 3, w = m % 3;
        const float* src = (w == 0) ? W3 : (w == 1) ? W4 : W5;
        Wt[idx] = f2bf(src[l * 16384 + f * 128 + g]);
    }

    if (tid < 64) diag_s[tid] = 0.f;

    // ---- stage x (64 rows) -> sT bf16 ----
    {
        const float4* xg4 = (const float4*)(x + (size_t)row0 * FF);
#pragma unroll
        for (int i = 0; i < 8; i++) {
            const int f4 = i * 256 + tid;
            const int row = f4 >> 5;
            const int k = (f4 & 31) * 4;
            float4 v = xg4[f4];
            ushort4 h;
            h.x = f2bf(v.x); h.y = f2bf(v.y); h.z = f2bf(v.z); h.w = f2bf(v.w);
            *(ushort4*)&sT[row * XS_STRIDE + k] = h;
        }
    }

    __threadfence(); grid.sync(); __threadfence();

    // ---- W0: w1(l0)->sW, w2t/xt->global, diag->diag_s ----
    write_xt64(sT, xt, tid, b, jloc0);
    {
        f32x4 a1[4][2], a2[4][2];
#pragma unroll
        for (int rt = 0; rt < 4; rt++)
#pragma unroll
            for (int ct = 0; ct < 2; ct++) { a1[rt][ct] = (f32x4)0.f; a2[rt][ct] = (f32x4)0.f; }
        mfma_AB64(sT, Wt, c, quad, ct0, a1);            // W3 l0
        mfma_AB64(sT, Wt + 16384, c, quad, ct0, a2);    // W4 l0
        w12_epilogue64(a1, a2, b3, b4, sW, w2t, diag_s, b, jloc0, c, quad, ct0);
    }

    __threadfence(); grid.sync(); __threadfence();

    // ---- S0 ----
    s_phase256(xt, w2t, St, red, blk, tid, wave, c, quad);

    __threadfence(); grid.sync(); __threadfence();

    // ---- O0 + W1 ----
    {
        const ushort* Sb = St + (size_t)b * (FF * FF);
        f32x4 accm[4][2];
#pragma unroll
        for (int rt = 0; rt < 4; rt++)
#pragma unroll
            for (int ct = 0; ct < 2; ct++) accm[rt][ct] = (f32x4)0.f;
        mfma_AB64(sW, Sb, c, quad, ct0, accm);          // w1(l0) @ S

#pragma unroll
        for (int rt = 0; rt < 4; rt++) {
            float dg[4];
#pragma unroll
            for (int r = 0; r < 4; r++) dg[r] = diag_s[rt * 16 + quad * 4 + r];
#pragma unroll
            for (int ct = 0; ct < 2; ct++) {
                const int gcol = (ct0 + ct) * 16 + c;
#pragma unroll
                for (int r = 0; r < 4; r++) {
                    const int lrow = rt * 16 + quad * 4 + r;
                    const float xv = x[(size_t)(row0 + lrow) * FF + gcol];
                    sT[lrow * XS_STRIDE + gcol] = f2bf((accm[rt][ct][r] - dg[r] * xv) * inv);
                }
            }
        }
        __syncthreads();            // msg in sT; all reads of sW/diag_s done
        if (tid < 64) diag_s[tid] = 0.f;   // reset for layer 1

        f32x4 acc2[4][2];
#pragma unroll
        for (int rt = 0; rt < 4; rt++)
#pragma unroll
            for (int ct = 0; ct < 2; ct++) acc2[rt][ct] = (f32x4)0.f;
        mfma_AB64(sT, Wt + 2 * 16384, c, quad, ct0, acc2);  // msg @ W5 l0

#pragma unroll
        for (int rt = 0; rt < 4; rt++) {
#pragma unroll
            for (int ct = 0; ct < 2; ct++) {
                const int gcol = (ct0 + ct) * 16 + c;
                const float bb = b5[gcol];
#pragma unroll
                for (int r = 0; r < 4; r++) {
                    const int lrow = rt * 16 + quad * 4 + r;
                    const float ov = lrelu(acc2[rt][ct][r] + bb) +
                                     x[(size_t)(row0 + lrow) * FF + gcol];
                    out[(size_t)(row0 + lrow) * FF + gcol] = ov;
                    sW[lrow * XS_STRIDE + gcol] = f2bf(ov);   // sW dead, reuse
                }
            }
        }
        __syncthreads();            // sW = out-bf16; reads of sT done

        // W1 from out tile in sW; w1(l1) -> sT
        write_xt64(sW, xt, tid, b, jloc0);
        f32x4 a1[4][2], a2[4][2];
#pragma unroll
        for (int rt = 0; rt < 4; rt++)
#pragma unroll
            for (int ct = 0; ct < 2; ct++) { a1[rt][ct] = (f32x4)0.f; a2[rt][ct] = (f32x4)0.f; }
        mfma_AB64(sW, Wt + 3 * 16384, c, quad, ct0, a1);    // W3 l1
        mfma_AB64(sW, Wt + 4 * 16384, c, quad, ct0, a2);    // W4 l1
        w12_epilogue64(a1, a2, b3 + FF, b4 + FF, sT, w2t, diag_s, b, jloc0, c, quad, ct0);
    }

    __threadfence(); grid.sync(); __threadfence();

    // ---- S1 ----
    s_phase256(xt, w2t, St, red, blk, tid, wave, c, quad);

    __threadfence(); grid.sync(); __threadfence();

    // ---- O1 (final) ----
    {
        const ushort* Sb = St + (size_t)b * (FF * FF);
        f32x4 accm[4][2];
#pragma unroll
        for (int rt = 0; rt < 4; rt++)
#pragma unroll
            for (int ct = 0; ct < 2; ct++) accm[rt][ct] = (f32x4)0.f;
        mfma_AB64(sT, Sb, c, quad, ct0, accm);          // w1(l1) @ S

#pragma unroll
        for (int rt = 0; rt < 4; rt++) {
            float dg[4];
#pragma unroll
            for (int r = 0; r < 4; r++) dg[r] = diag_s[rt * 16 + quad * 4 + r];
#pragma unroll
            for (int ct = 0; ct < 2; ct++) {
                const int gcol = (ct0 + ct) * 16 + c;
#pragma unroll
                for (int r = 0; r < 4; r++) {
                    const int lrow = rt * 16 + quad * 4 + r;
                    const float xv = out[(size_t)(row0 + lrow) * FF + gcol];
                    sW[lrow * XS_STRIDE + gcol] = f2bf((accm[rt][ct][r] - dg[r] * xv) * inv);
                }
            }
        }
        __syncthreads();

        f32x4 acc2[4][2];
#pragma unroll
        for (int rt = 0; rt < 4; rt++)
#pragma unroll
            for (int ct = 0; ct < 2; ct++) acc2[rt][ct] = (f32x4)0.f;
        mfma_AB64(sW, Wt + 5 * 16384, c, quad, ct0, acc2);  // msg @ W5 l1

#pragma unroll
        for (int rt = 0; rt < 4; rt++) {
#pragma unroll
            for (int ct = 0; ct < 2; ct++) {
                const int gcol = (ct0 + ct) * 16 + c;
                const float bb = b5[FF + gcol];
#pragma unroll
                for (int r = 0; r < 4; r++) {
                    const int lrow = rt * 16 + quad * 4 + r;
                    const size_t oidx = (size_t)(row0 + lrow) * FF + gcol;
                    out[oidx] = lrelu(acc2[rt][ct][r] + bb) + out[oidx];
                }
            }
        }
    }
}

// ===========================================================================
// Fallback kernels (round-3, proven: 123 us)
// ===========================================================================

__global__ __launch_bounds__(256) void k_prep(
    const float* __restrict__ W3, const float* __restrict__ W4,
    const float* __restrict__ W5, ushort* __restrict__ Wt)
{
    const int idx = blockIdx.x * 256 + threadIdx.x;
    const int m = idx >> 14;
    const int rem = idx & 16383;
    const int f = rem & 127;
    const int g = rem >> 7;
    const int l = m / 3, w = m % 3;
    const float* src = (w == 0) ? W3 : (w == 1) ? W4 : W5;
    Wt[m * 16384 + g * 128 + f] = f2bf(src[l * 16384 + f * 128 + g]);
}

__global__ __launch_bounds__(256) void k_w12(
    const float* __restrict__ x, const ushort* __restrict__ w3t,
    const ushort* __restrict__ w4t, const float* __restrict__ b3,
    const float* __restrict__ b4, ushort* __restrict__ w1b,
    ushort* __restrict__ w2t, ushort* __restrict__ xt,
    float* __restrict__ diag)
{
    __shared__ ushort xs[32 * XS_STRIDE];
    __shared__ float diag_s[32];

    const int tid = threadIdx.x;
    const int row0 = blockIdx.x * 32;
    const int b = row0 >> 11;
    const int jloc0 = row0 & 2047;

    if (tid < 32) diag_s[tid] = 0.f;

    const float4* xg4 = (const float4*)(x + (size_t)row0 * FF);
#pragma unroll
    for (int i = 0; i < 4; i++) {
        const int f4 = i * 256 + tid;
        const int row = f4 >> 5;
        const int k = (f4 & 31) * 4;
        float4 v = xg4[f4];
        ushort4 h;
        h.x = f2bf(v.x); h.y = f2bf(v.y); h.z = f2bf(v.z); h.w = f2bf(v.w);
        *(ushort4*)&xs[row * XS_STRIDE + k] = h;
    }
    __syncthreads();

    write_xt32(xs, xt, tid, b, jloc0);

    const int lane = tid & 63;
    const int wave = tid >> 6;
    const int c = lane & 15;
    const int quad = lane >> 4;
    const int ct0 = wave * 2;

    f32x4 a1[2][2], a2[2][2];
#pragma unroll
    for (int rt = 0; rt < 2; rt++)
#pragma unroll
        for (int ct = 0; ct < 2; ct++) { a1[rt][ct] = (f32x4)0.f; a2[rt][ct] = (f32x4)0.f; }
    mfma_AB(xs, w3t, c, quad, ct0, a1);
    mfma_AB(xs, w4t, c, quad, ct0, a2);

    // w1 to global (row-major positions == LDS positions w/ FF stride)
    float dpar[2][4];
#pragma unroll
    for (int rt = 0; rt < 2; rt++)
#pragma unroll
        for (int r = 0; r < 4; r++) dpar[rt][r] = 0.f;
#pragma unroll
    for (int rt = 0; rt < 2; rt++) {
#pragma unroll
        for (int ct = 0; ct < 2; ct++) {
            const int gcol = (ct0 + ct) * 16 + c;
            const float bb3 = b3[gcol], bb4 = b4[gcol];
            ushort w2p[4];
#pragma unroll
            for (int r = 0; r < 4; r++) {
                const float v1 = lrelu(a1[rt][ct][r] + bb3);
                const float v2 = lrelu(a2[rt][ct][r] + bb4);
                const int grow = row0 + rt * 16 + quad * 4 + r;
                w1b[(size_t)grow * FF + gcol] = f2bf(v1);
                w2p[r] = f2bf(v2);
                dpar[rt][r] += v1 * v2;
            }
            const uint lo = (uint)w2p[0] | ((uint)w2p[1] << 16);
            const uint hi = (uint)w2p[2] | ((uint)w2p[3] << 16);
            *(uint2*)&w2t[(size_t)b * (FF * NN) + (size_t)gcol * NN +
                          jloc0 + rt * 16 + quad * 4] = make_uint2(lo, hi);
        }
    }
#pragma unroll
    for (int rt = 0; rt < 2; rt++) {
#pragma unroll
        for (int r = 0; r < 4; r++) {
            float dp = dpar[rt][r];
            dp += __shfl_xor(dp, 1, 64);
            dp += __shfl_xor(dp, 2, 64);
            dp += __shfl_xor(dp, 4, 64);
            dp += __shfl_xor(dp, 8, 64);
            if (c == 0) atomicAdd(&diag_s[rt * 16 + quad * 4 + r], dp);
        }
    }
    __syncthreads();
    if (tid < 32) diag[row0 + tid] = diag_s[tid];
}

__global__ __launch_bounds__(256) void k_S2(
    const ushort* __restrict__ xt, const ushort* __restrict__ w2t,
    ushort* __restrict__ St)
{
    __shared__ float red[4][512];
    const int tid = threadIdx.x;
    const int wave = tid >> 6;
    const int c = tid & 15;
    const int quad = (tid & 63) >> 4;
    s_phase256(xt, w2t, St, red, blockIdx.x, tid, wave, c, quad);
}

__global__ __launch_bounds__(256) void k_out(
    const float* __restrict__ x, const ushort* __restrict__ w1b,
    const ushort* __restrict__ St, const float* __restrict__ diag,
    const ushort* __restrict__ w5t, const float* __restrict__ b5,
    float* __restrict__ out)
{
    __shared__ ushort w1s[32 * XS_STRIDE];
    __shared__ ushort ms[32 * XS_STRIDE];

    const int tid = threadIdx.x;
    const int row0 = blockIdx.x * 32;
    const int b = row0 >> 11;
    const ushort* Sb = St + (size_t)b * (FF * FF);

#pragma unroll
    for (int i = 0; i < 2; i++) {
        const int off = (i * 256 + tid) * 8;
        const int row = off >> 7;
        const int k = off & 127;
        *(short8*)&w1s[row * XS_STRIDE + k] = *(const short8*)&w1b[(size_t)row0 * FF + off];
    }
    __syncthreads();

    const int lane = tid & 63;
    const int wave = tid >> 6;
    const int c = lane & 15;
    const int quad = lane >> 4;
    const int ct0 = wave * 2;

    f32x4 accm[2][2];
#pragma unroll
    for (int rt = 0; rt < 2; rt++)
#pragma unroll
        for (int ct = 0; ct < 2; ct++) accm[rt][ct] = (f32x4)0.f;
    mfma_AB(w1s, Sb, c, quad, ct0, accm);

    const float inv = 1.f / (float)(NN - 1);
    float xsv[2][2][4];
#pragma unroll
    for (int rt = 0; rt < 2; rt++) {
        float dg[4];
#pragma unroll
        for (int r = 0; r < 4; r++) dg[r] = diag[row0 + rt * 16 + quad * 4 + r];
#pragma unroll
        for (int ct = 0; ct < 2; ct++) {
            const int gcol = (ct0 + ct) * 16 + c;
#pragma unroll
            for (int r = 0; r < 4; r++) {
                const int lrow = rt * 16 + quad * 4 + r;
                const float xv = x[(size_t)(row0 + lrow) * FF + gcol];
                xsv[rt][ct][r] = xv;
                ms[lrow * XS_STRIDE + gcol] = f2bf((accm[rt][ct][r] - dg[r] * xv) * inv);
            }
        }
    }
    __syncthreads();

    f32x4 acc2[2][2];
#pragma unroll
    for (int rt = 0; rt < 2; rt++)
#pragma unroll
        for (int ct = 0; ct < 2; ct++) acc2[rt][ct] = (f32x4)0.f;
    mfma_AB(ms, w5t, c, quad, ct0, acc2);

#pragma unroll
    for (int rt = 0; rt < 2; rt++) {
#pragma unroll
        for (int ct = 0; ct < 2; ct++) {
            const int gcol = (ct0 + ct) * 16 + c;
            const float bb = b5[gcol];
#pragma unroll
            for (int r = 0; r < 4; r++) {
                const int grow = row0 + rt * 16 + quad * 4 + r;
                out[(size_t)grow * FF + gcol] = lrelu(acc2[rt][ct][r] + bb) + xsv[rt][ct][r];
            }
        }
    }
}

__global__ __launch_bounds__(256) void k_out_w12(
    const float* __restrict__ x, const ushort* __restrict__ w1b_in,
    const ushort* __restrict__ St, const float* __restrict__ diag_in,
    const ushort* __restrict__ w5t, const float* __restrict__ b5,
    float* __restrict__ out,
    const ushort* __restrict__ w3t, const ushort* __restrict__ w4t,
    const float* __restrict__ b3, const float* __restrict__ b4,
    ushort* __restrict__ w1b, ushort* __restrict__ w2t,
    ushort* __restrict__ xt, float* __restrict__ diag)
{
    __shared__ ushort sA[32 * XS_STRIDE];
    __shared__ ushort sB[32 * XS_STRIDE];
    __shared__ float diag_s[32];

    const int tid = threadIdx.x;
    const int row0 = blockIdx.x * 32;
    const int b = row0 >> 11;
    const int jloc0 = row0 & 2047;
    const ushort* Sb = St + (size_t)b * (FF * FF);

    if (tid < 32) diag_s[tid] = 0.f;

#pragma unroll
    for (int i = 0; i < 2; i++) {
        const int off = (i * 256 + tid) * 8;
        const int row = off >> 7;
        const int k = off & 127;
        *(short8*)&sA[row * XS_STRIDE + k] = *(const short8*)&w1b_in[(size_t)row0 * FF + off];
    }
    __syncthreads();

    const int lane = tid & 63;
    const int wave = tid >> 6;
    const int c = lane & 15;
    const int quad = lane >> 4;
    const int ct0 = wave * 2;

    f32x4 accm[2][2];
#pragma unroll
    for (int rt = 0; rt < 2; rt++)
#pragma unroll
        for (int ct = 0; ct < 2; ct++) accm[rt][ct] = (f32x4)0.f;
    mfma_AB(sA, Sb, c, quad, ct0, accm);

    const float inv = 1.f / (float)(NN - 1);
    float xsv[2][2][4];
#pragma unroll
    for (int rt = 0; rt < 2; rt++) {
        float dg[4];
#pragma unroll
        for (int r = 0; r < 4; r++) dg[r] = diag_in[row0 + rt * 16 + quad * 4 + r];
#pragma unroll
        for (int ct = 0; ct < 2; ct++) {
            const int gcol = (ct0 + ct) * 16 + c;
#pragma unroll
            for (int r = 0; r < 4; r++) {
                const int lrow = rt * 16 + quad * 4 + r;
                const float xv = x[(size_t)(row0 + lrow) * FF + gcol];
                xsv[rt][ct][r] = xv;
                sB[lrow * XS_STRIDE + gcol] = f2bf((accm[rt][ct][r] - dg[r] * xv) * inv);
            }
        }
    }
    __syncthreads();

    f32x4 acc2[2][2];
#pragma unroll
    for (int rt = 0; rt < 2; rt++)
#pragma unroll
        for (int ct = 0; ct < 2; ct++) acc2[rt][ct] = (f32x4)0.f;
    mfma_AB(sB, w5t, c, quad, ct0, acc2);

#pragma unroll
    for (int rt = 0; rt < 2; rt++) {
#pragma unroll
        for (int ct = 0; ct < 2; ct++) {
            const int gcol = (ct0 + ct) * 16 + c;
            const float bb = b5[gcol];
#pragma unroll
            for (int r = 0; r < 4; r++) {
                const int lrow = rt * 16 + quad * 4 + r;
                const float ov = lrelu(acc2[rt][ct][r] + bb) + xsv[rt][ct][r];
                out[(size_t)(row0 + lrow) * FF + gcol] = ov;
                sA[lrow * XS_STRIDE + gcol] = f2bf(ov);
            }
        }
    }
    __syncthreads();

    write_xt32(sA, xt, tid, b, jloc0);
    f32x4 a1[2][2], a2[2][2];
#pragma unroll
    for (int rt = 0; rt < 2; rt++)
#pragma unroll
        for (int ct = 0; ct < 2; ct++) { a1[rt][ct] = (f32x4)0.f; a2[rt][ct] = (f32x4)0.f; }
    mfma_AB(sA, w3t, c, quad, ct0, a1);
    mfma_AB(sA, w4t, c, quad, ct0, a2);

    float dpar[2][4];
#pragma unroll
    for (int rt = 0; rt < 2; rt++)
#pragma unroll
        for (int r = 0; r < 4; r++) dpar[rt][r] = 0.f;
#pragma unroll
    for (int rt = 0; rt < 2; rt++) {
#pragma unroll
        for (int ct = 0; ct < 2; ct++) {
            const int gcol = (ct0 + ct) * 16 + c;
            const float bb3 = b3[gcol], bb4 = b4[gcol];
            ushort w2p[4];
#pragma unroll
            for (int r = 0; r < 4; r++) {
                const float v1 = lrelu(a1[rt][ct][r] + bb3);
                const float v2 = lrelu(a2[rt][ct][r] + bb4);
                const int grow = row0 + rt * 16 + quad * 4 + r;
                w1b[(size_t)grow * FF + gcol] = f2bf(v1);
                w2p[r] = f2bf(v2);
                dpar[rt][r] += v1 * v2;
            }
            const uint lo = (uint)w2p[0] | ((uint)w2p[1] << 16);
            const uint hi = (uint)w2p[2] | ((uint)w2p[3] << 16);
            *(uint2*)&w2t[(size_t)b * (FF * NN) + (size_t)gcol * NN +
                          jloc0 + rt * 16 + quad * 4] = make_uint2(lo, hi);
        }
    }
#pragma unroll
    for (int rt = 0; rt < 2; rt++) {
#pragma unroll
        for (int r = 0; r < 4; r++) {
            float dp = dpar[rt][r];
            dp += __shfl_xor(dp, 1, 64);
            dp += __shfl_xor(dp, 2, 64);
            dp += __shfl_xor(dp, 4, 64);
            dp += __shfl_xor(dp, 8, 64);
            if (c == 0) atomicAdd(&diag_s[rt * 16 + quad * 4 + r], dp);
        }
    }
    __syncthreads();
    if (tid < 32) diag[row0 + tid] = diag_s[tid];
}

// ---------------------------------------------------------------------------
extern "C" void kernel_launch(void* const* d_in, const int* in_sizes, int n_in,
                              void* d_out, int out_size, void* d_ws, size_t ws_size,
                              hipStream_t stream)
{
    const float* x  = (const float*)d_in[0];
    const float* W3 = (const float*)d_in[1];
    const float* b3 = (const float*)d_in[2];
    const float* W4 = (const float*)d_in[3];
    const float* b4 = (const float*)d_in[4];
    const float* W5 = (const float*)d_in[5];
    const float* b5 = (const float*)d_in[6];
    float* out = (float*)d_out;

    char* ws = (char*)d_ws;
    ushort* w1b  = (ushort*)(ws);                        // 4 MB (fallback only)
    ushort* w2t  = (ushort*)(ws + ((size_t)4  << 20));   // 4 MB
    ushort* xt   = (ushort*)(ws + ((size_t)8  << 20));   // 4 MB
    float*  diag = (float*) (ws + ((size_t)12 << 20));   // 64 KB (fallback only)
    ushort* St   = (ushort*)(ws + ((size_t)13 << 20));   // 256 KB
    ushort* Wt   = (ushort*)(ws + ((size_t)13 << 20) + (512 << 10));  // 192 KB

    void* args[] = {
        (void*)&x, (void*)&W3, (void*)&b3, (void*)&W4, (void*)&b4,
        (void*)&W5, (void*)&b5, (void*)&out, (void*)&w2t, (void*)&xt,
        (void*)&St, (void*)&Wt
    };
    hipError_t e = hipLaunchCooperativeKernel((void*)k_all, dim3(256), dim3(256),
                                              args, 0, stream);
    if (e != hipSuccess) {
        (void)hipGetLastError();   // clear sticky error, use multi-kernel path
        k_prep<<<384, 256, 0, stream>>>(W3, W4, W5, Wt);
        k_w12<<<512, 256, 0, stream>>>(x, Wt, Wt + 16384, b3, b4, w1b, w2t, xt, diag);
        k_S2<<<256, 256, 0, stream>>>(xt, w2t, St);
        k_out_w12<<<512, 256, 0, stream>>>(x, w1b, St, diag, Wt + 2 * 16384, b5, out,
                                           Wt + 3 * 16384, Wt + 4 * 16384,
                                           b3 + FF, b4 + FF, w1b, w2t, xt, diag);
        k_S2<<<256, 256, 0, stream>>>(xt, w2t, St);
        k_out<<<512, 256, 0, stream>>>(out, w1b, St, diag, Wt + 5 * 16384, b5 + FF, out);
    }
}

// Round 6
// 136.201 us; speedup vs baseline: 3.2931x; 3.2931x over previous
//
#include <hip/hip_runtime.h>

#define NN 2048
#define FF 128
#define SLOPE 0.1f
#define LS 136              // padded bf16 row stride in LDS (64-row tiles)

typedef __attribute__((ext_vector_type(8))) short short8;
typedef __attribute__((ext_vector_type(4))) float f32x4;

__device__ __forceinline__ float lrelu(float v) { return v >= 0.f ? v : SLOPE * v; }

__device__ __forceinline__ ushort f2bf(float f) {
    uint u = __float_as_uint(f);
    return (ushort)((u + 0x7fffu + ((u >> 16) & 1u)) >> 16);
}

// ---------------------------------------------------------------------------
// 64-row tile helpers (correctness-proven in the round-5 coop kernel)
// ---------------------------------------------------------------------------

// acc[4][2] += A(64x128 LDS, stride LS) @ B^T (global [n][128])
__device__ __forceinline__ void mfma_AB64(
    const ushort* __restrict__ As, const ushort* __restrict__ Bg,
    int c, int quad, int ct0, f32x4 acc[4][2])
{
#pragma unroll
    for (int kk = 0; kk < 4; kk++) {
        short8 a[4];
#pragma unroll
        for (int rt = 0; rt < 4; rt++)
            a[rt] = *(const short8*)&As[(rt * 16 + c) * LS + kk * 32 + quad * 8];
#pragma unroll
        for (int ct = 0; ct < 2; ct++) {
            const int n = (ct0 + ct) * 16 + c;
            short8 bf = *(const short8*)&Bg[n * 128 + kk * 32 + quad * 8];
#pragma unroll
            for (int rt = 0; rt < 4; rt++)
                acc[rt][ct] = __builtin_amdgcn_mfma_f32_16x16x32_bf16(a[rt], bf, acc[rt][ct], 0, 0, 0);
        }
    }
}

// transposed write: dstb[g][jloc0 + 0..63] = s[j][g]; 64 B contiguous / thread
__device__ __forceinline__ void write_t64(
    const ushort* __restrict__ s, ushort* __restrict__ dstb,
    int jloc0, int tid)
{
    const int g = tid >> 1;
    const int h = tid & 1;
    uint p[16];
#pragma unroll
    for (int jj = 0; jj < 16; jj++) {
        const uint lo = s[(h * 32 + jj * 2) * LS + g];
        const uint hi = s[(h * 32 + jj * 2 + 1) * LS + g];
        p[jj] = lo | (hi << 16);
    }
    uint4* dst = (uint4*)&dstb[(size_t)g * NN + jloc0 + h * 32];
    dst[0] = make_uint4(p[0], p[1], p[2], p[3]);
    dst[1] = make_uint4(p[4], p[5], p[6], p[7]);
    dst[2] = make_uint4(p[8], p[9], p[10], p[11]);
    dst[3] = make_uint4(p[12], p[13], p[14], p[15]);
}

// linear copy LDS tile (stride LS) -> global row-major [64][128]
__device__ __forceinline__ void store_lin64(
    const ushort* __restrict__ s, ushort* __restrict__ g, int tid)
{
#pragma unroll
    for (int i = 0; i < 4; i++) {
        const int off = (i * 256 + tid) * 8;
        *(short8*)&g[off] = *(const short8*)&s[(off >> 7) * LS + (off & 127)];
    }
}

// linear copy global row-major [64][128] -> LDS tile (stride LS)
__device__ __forceinline__ void load_lin64(
    const ushort* __restrict__ g, ushort* __restrict__ s, int tid)
{
#pragma unroll
    for (int i = 0; i < 4; i++) {
        const int off = (i * 256 + tid) * 8;
        *(short8*)&s[(off >> 7) * LS + (off & 127)] = *(const short8*)&g[off];
    }
}

// lrelu+bias epilogue for the twin w1/w2 GEMMs; both results -> LDS tiles
__device__ __forceinline__ void epi_w12(
    const f32x4 acc1[4][2], const f32x4 acc2[4][2],
    const float* __restrict__ b3, const float* __restrict__ b4,
    ushort* __restrict__ w1s, ushort* __restrict__ w2s, float* __restrict__ diag_s,
    int c, int quad, int ct0)
{
    float dpar[4][4];
#pragma unroll
    for (int rt = 0; rt < 4; rt++)
#pragma unroll
        for (int r = 0; r < 4; r++) dpar[rt][r] = 0.f;

#pragma unroll
    for (int rt = 0; rt < 4; rt++) {
#pragma unroll
        for (int ct = 0; ct < 2; ct++) {
            const int gcol = (ct0 + ct) * 16 + c;
            const float bb3 = b3[gcol], bb4 = b4[gcol];
#pragma unroll
            for (int r = 0; r < 4; r++) {
                const float v1 = lrelu(acc1[rt][ct][r] + bb3);
                const float v2 = lrelu(acc2[rt][ct][r] + bb4);
                const int lrow = rt * 16 + quad * 4 + r;
                w1s[lrow * LS + gcol] = f2bf(v1);
                w2s[lrow * LS + gcol] = f2bf(v2);
                dpar[rt][r] += v1 * v2;
            }
        }
    }
#pragma unroll
    for (int rt = 0; rt < 4; rt++) {
#pragma unroll
        for (int r = 0; r < 4; r++) {
            float dp = dpar[rt][r];
            dp += __shfl_xor(dp, 1, 64);
            dp += __shfl_xor(dp, 2, 64);
            dp += __shfl_xor(dp, 4, 64);
            dp += __shfl_xor(dp, 8, 64);
            if (c == 0) atomicAdd(&diag_s[rt * 16 + quad * 4 + r], dp);
        }
    }
}

// ---------------------------------------------------------------------------
// K0: bf16 weight transpose Wt[m][g][f] = W[m][f][g]
// ---------------------------------------------------------------------------
__global__ __launch_bounds__(256) void k_prep(
    const float* __restrict__ W3, const float* __restrict__ W4,
    const float* __restrict__ W5, ushort* __restrict__ Wt)
{
    const int idx = blockIdx.x * 256 + threadIdx.x;
    const int m = idx >> 14;
    const int rem = idx & 16383;
    const int f = rem & 127;
    const int g = rem >> 7;
    const int l = m / 3, w = m % 3;
    const float* src = (w == 0) ? W3 : (w == 1) ? W4 : W5;
    Wt[m * 16384 + g * 128 + f] = f2bf(src[l * 16384 + f * 128 + g]);
}

// ---------------------------------------------------------------------------
// K1: 256 blocks x 64 rows. w1b (row-major), w2t+xt (transposed), diag.
// ---------------------------------------------------------------------------
__global__ __launch_bounds__(256, 2) void k_w12(
    const float* __restrict__ x, const ushort* __restrict__ w3t,
    const ushort* __restrict__ w4t, const float* __restrict__ b3,
    const float* __restrict__ b4, ushort* __restrict__ w1b,
    ushort* __restrict__ w2t, ushort* __restrict__ xt,
    float* __restrict__ diag)
{
    __shared__ ushort xs[64 * LS];
    __shared__ ushort w2s[64 * LS];
    __shared__ float diag_s[64];

    const int tid = threadIdx.x;
    const int row0 = blockIdx.x * 64;
    const int b = blockIdx.x >> 5;
    const int jloc0 = row0 & 2047;

    if (tid < 64) diag_s[tid] = 0.f;

    // stage x (fp32) -> bf16 LDS
    const float4* xg4 = (const float4*)(x + (size_t)row0 * FF);
#pragma unroll
    for (int i = 0; i < 8; i++) {
        const int f4 = i * 256 + tid;
        const int row = f4 >> 5;
        const int k = (f4 & 31) * 4;
        float4 v = xg4[f4];
        ushort4 h;
        h.x = f2bf(v.x); h.y = f2bf(v.y); h.z = f2bf(v.z); h.w = f2bf(v.w);
        *(ushort4*)&xs[row * LS + k] = h;
    }
    __syncthreads();

    write_t64(xs, xt + (size_t)b * (FF * NN), jloc0, tid);

    const int lane = tid & 63;
    const int wave = tid >> 6;
    const int c = lane & 15;
    const int quad = lane >> 4;
    const int ct0 = wave * 2;

    f32x4 a1[4][2], a2[4][2];
#pragma unroll
    for (int rt = 0; rt < 4; rt++)
#pragma unroll
        for (int ct = 0; ct < 2; ct++) { a1[rt][ct] = (f32x4)0.f; a2[rt][ct] = (f32x4)0.f; }
    mfma_AB64(xs, w3t, c, quad, ct0, a1);
    mfma_AB64(xs, w4t, c, quad, ct0, a2);

    __syncthreads();   // all xs reads done; reuse xs as w1 staging
    epi_w12(a1, a2, b3, b4, xs, w2s, diag_s, c, quad, ct0);
    __syncthreads();

    store_lin64(xs, w1b + (size_t)row0 * FF, tid);
    write_t64(w2s, w2t + (size_t)b * (FF * NN), jloc0, tid);
    if (tid < 64) diag[row0 + tid] = diag_s[tid];
}

// ---------------------------------------------------------------------------
// K2: St[b][g][f] = bf16( sum_j xt[b][g][j]*w2t[b][f][j] ).  512 blocks (2/CU),
// one 16x16 tile per block, 4 waves split K=2048.
// ---------------------------------------------------------------------------
__global__ __launch_bounds__(256, 2) void k_S(
    const ushort* __restrict__ xt, const ushort* __restrict__ w2t,
    ushort* __restrict__ St)
{
    __shared__ float red[4][256];
    const int tid = threadIdx.x;
    const int lane = tid & 63;
    const int wave = tid >> 6;
    const int c = lane & 15;
    const int quad = lane >> 4;

    const int sb = blockIdx.x >> 6;        // batch
    const int gq = (blockIdx.x >> 3) & 7;  // 16-g group
    const int fs = blockIdx.x & 7;         // 16-f group

    const int j0 = wave * 512 + quad * 8;
    const ushort* ap = &xt[(size_t)sb * (FF * NN) + (size_t)(gq * 16 + c) * NN + j0];
    const ushort* bp = &w2t[(size_t)sb * (FF * NN) + (size_t)(fs * 16 + c) * NN + j0];

    f32x4 acc = (f32x4)0.f;
#pragma unroll
    for (int it = 0; it < 16; it++) {
        short8 a = *(const short8*)(ap + it * 32);
        short8 bv = *(const short8*)(bp + it * 32);
        acc = __builtin_amdgcn_mfma_f32_16x16x32_bf16(a, bv, acc, 0, 0, 0);
    }
#pragma unroll
    for (int r = 0; r < 4; r++) red[wave][(quad * 4 + r) * 16 + c] = acc[r];
    __syncthreads();

    const float s = red[0][tid] + red[1][tid] + red[2][tid] + red[3][tid];
    const int gl = tid >> 4, fl = tid & 15;
    St[(size_t)sb * (FF * FF) + (size_t)(gq * 16 + gl) * FF + fs * 16 + fl] = f2bf(s);
}

// ---------------------------------------------------------------------------
// K3: out = lrelu((w1@S - diag*x)/(N-1) @ W5 + b5) + x.  256 blocks x 64 rows.
// ---------------------------------------------------------------------------
__global__ __launch_bounds__(256, 2) void k_out(
    const float* __restrict__ xin, const ushort* __restrict__ w1b,
    const ushort* __restrict__ St, const float* __restrict__ diag,
    const ushort* __restrict__ w5t, const float* __restrict__ b5,
    float* __restrict__ out)
{
    __shared__ ushort sW[64 * LS];
    __shared__ ushort sT[64 * LS];

    const int tid = threadIdx.x;
    const int row0 = blockIdx.x * 64;
    const int b = blockIdx.x >> 5;
    const ushort* Sb = St + (size_t)b * (FF * FF);

    load_lin64(w1b + (size_t)row0 * FF, sW, tid);
    __syncthreads();

    const int lane = tid & 63;
    const int wave = tid >> 6;
    const int c = lane & 15;
    const int quad = lane >> 4;
    const int ct0 = wave * 2;

    f32x4 accm[4][2];
#pragma unroll
    for (int rt = 0; rt < 4; rt++)
#pragma unroll
        for (int ct = 0; ct < 2; ct++) accm[rt][ct] = (f32x4)0.f;
    mfma_AB64(sW, Sb, c, quad, ct0, accm);

    const float inv = 1.f / (float)(NN - 1);
    float xsv[4][2][4];
#pragma unroll
    for (int rt = 0; rt < 4; rt++) {
        float dg[4];
#pragma unroll
        for (int r = 0; r < 4; r++) dg[r] = diag[row0 + rt * 16 + quad * 4 + r];
#pragma unroll
        for (int ct = 0; ct < 2; ct++) {
            const int gcol = (ct0 + ct) * 16 + c;
#pragma unroll
            for (int r = 0; r < 4; r++) {
                const int lrow = rt * 16 + quad * 4 + r;
                const float xv = xin[(size_t)(row0 + lrow) * FF + gcol];
                xsv[rt][ct][r] = xv;
                sT[lrow * LS + gcol] = f2bf((accm[rt][ct][r] - dg[r] * xv) * inv);
            }
        }
    }
    __syncthreads();

    f32x4 acc2[4][2];
#pragma unroll
    for (int rt = 0; rt < 4; rt++)
#pragma unroll
        for (int ct = 0; ct < 2; ct++) acc2[rt][ct] = (f32x4)0.f;
    mfma_AB64(sT, w5t, c, quad, ct0, acc2);

#pragma unroll
    for (int rt = 0; rt < 4; rt++) {
#pragma unroll
        for (int ct = 0; ct < 2; ct++) {
            const int gcol = (ct0 + ct) * 16 + c;
            const float bb = b5[gcol];
#pragma unroll
            for (int r = 0; r < 4; r++) {
                const int lrow = rt * 16 + quad * 4 + r;
                out[(size_t)(row0 + lrow) * FF + gcol] =
                    lrelu(acc2[rt][ct][r] + bb) + xsv[rt][ct][r];
            }
        }
    }
}

// ---------------------------------------------------------------------------
// K4: fused out(layer l) + w12(layer l+1).  256 blocks x 64 rows.
// Per-block aliasing on w1b/diag is safe (reads precede writes, same rows).
// ---------------------------------------------------------------------------
__global__ __launch_bounds__(256, 2) void k_out_w12(
    const float* __restrict__ x, const ushort* __restrict__ w1b_in,
    const ushort* __restrict__ St, const float* __restrict__ diag_in,
    const ushort* __restrict__ w5t, const float* __restrict__ b5,
    float* __restrict__ out,
    const ushort* __restrict__ w3t, const ushort* __restrict__ w4t,
    const float* __restrict__ b3, const float* __restrict__ b4,
    ushort* __restrict__ w1b, ushort* __restrict__ w2t,
    ushort* __restrict__ xt, float* __restrict__ diag)
{
    __shared__ ushort sW[64 * LS];
    __shared__ ushort sT[64 * LS];
    __shared__ float diag_s[64];

    const int tid = threadIdx.x;
    const int row0 = blockIdx.x * 64;
    const int b = blockIdx.x >> 5;
    const int jloc0 = row0 & 2047;
    const ushort* Sb = St + (size_t)b * (FF * FF);

    if (tid < 64) diag_s[tid] = 0.f;

    load_lin64(w1b_in + (size_t)row0 * FF, sW, tid);
    __syncthreads();

    const int lane = tid & 63;
    const int wave = tid >> 6;
    const int c = lane & 15;
    const int quad = lane >> 4;
    const int ct0 = wave * 2;

    // ---- phase A: msg = (w1@S - diag*x)/(N-1) ----
    f32x4 accm[4][2];
#pragma unroll
    for (int rt = 0; rt < 4; rt++)
#pragma unroll
        for (int ct = 0; ct < 2; ct++) accm[rt][ct] = (f32x4)0.f;
    mfma_AB64(sW, Sb, c, quad, ct0, accm);

    const float inv = 1.f / (float)(NN - 1);
    float xsv[4][2][4];
#pragma unroll
    for (int rt = 0; rt < 4; rt++) {
        float dg[4];
#pragma unroll
        for (int r = 0; r < 4; r++) dg[r] = diag_in[row0 + rt * 16 + quad * 4 + r];
#pragma unroll
        for (int ct = 0; ct < 2; ct++) {
            const int gcol = (ct0 + ct) * 16 + c;
#pragma unroll
            for (int r = 0; r < 4; r++) {
                const int lrow = rt * 16 + quad * 4 + r;
                const float xv = x[(size_t)(row0 + lrow) * FF + gcol];
                xsv[rt][ct][r] = xv;
                sT[lrow * LS + gcol] = f2bf((accm[rt][ct][r] - dg[r] * xv) * inv);
            }
        }
    }
    __syncthreads();   // sT = msg; all sW reads done

    // ---- phase B: out = lrelu(msg@W5 + b5) + x ----
    f32x4 acc2[4][2];
#pragma unroll
    for (int rt = 0; rt < 4; rt++)
#pragma unroll
        for (int ct = 0; ct < 2; ct++) acc2[rt][ct] = (f32x4)0.f;
    mfma_AB64(sT, w5t, c, quad, ct0, acc2);

#pragma unroll
    for (int rt = 0; rt < 4; rt++) {
#pragma unroll
        for (int ct = 0; ct < 2; ct++) {
            const int gcol = (ct0 + ct) * 16 + c;
            const float bb = b5[gcol];
#pragma unroll
            for (int r = 0; r < 4; r++) {
                const int lrow = rt * 16 + quad * 4 + r;
                const float ov = lrelu(acc2[rt][ct][r] + bb) + xsv[rt][ct][r];
                out[(size_t)(row0 + lrow) * FF + gcol] = ov;
                sW[lrow * LS + gcol] = f2bf(ov);   // sW dead, becomes out tile
            }
        }
    }
    __syncthreads();   // sW = out-bf16 complete; sT reads done

    // ---- phase C: next layer's w12 from the out tile ----
    write_t64(sW, xt + (size_t)b * (FF * NN), jloc0, tid);

    f32x4 a1[4][2], a2[4][2];
#pragma unroll
    for (int rt = 0; rt < 4; rt++)
#pragma unroll
        for (int ct = 0; ct < 2; ct++) { a1[rt][ct] = (f32x4)0.f; a2[rt][ct] = (f32x4)0.f; }
    mfma_AB64(sW, w3t, c, quad, ct0, a1);
    mfma_AB64(sW, w4t, c, quad, ct0, a2);

    __syncthreads();   // all sW reads done; sT free
    epi_w12(a1, a2, b3, b4, sT /*w1'*/, sW /*w2'*/, diag_s, c, quad, ct0);
    __syncthreads();

    store_lin64(sT, w1b + (size_t)row0 * FF, tid);
    write_t64(sW, w2t + (size_t)b * (FF * NN), jloc0, tid);
    if (tid < 64) diag[row0 + tid] = diag_s[tid];
}

// ---------------------------------------------------------------------------
extern "C" void kernel_launch(void* const* d_in, const int* in_sizes, int n_in,
                              void* d_out, int out_size, void* d_ws, size_t ws_size,
                              hipStream_t stream)
{
    const float* x  = (const float*)d_in[0];
    const float* W3 = (const float*)d_in[1];
    const float* b3 = (const float*)d_in[2];
    const float* W4 = (const float*)d_in[3];
    const float* b4 = (const float*)d_in[4];
    const float* W5 = (const float*)d_in[5];
    const float* b5 = (const float*)d_in[6];
    float* out = (float*)d_out;

    char* ws = (char*)d_ws;
    ushort* w1b  = (ushort*)(ws);                        // 4 MB bf16 [16384][128]
    ushort* w2t  = (ushort*)(ws + ((size_t)4  << 20));   // 4 MB bf16 [8][128][2048]
    ushort* xt   = (ushort*)(ws + ((size_t)8  << 20));   // 4 MB bf16 [8][128][2048]
    float*  diag = (float*) (ws + ((size_t)12 << 20));   // 64 KB fp32 [16384]
    ushort* St   = (ushort*)(ws + ((size_t)13 << 20));   // 256 KB bf16 [8][128][128]
    ushort* Wt   = (ushort*)(ws + ((size_t)13 << 20) + (512 << 10));  // 192 KB

    k_prep<<<384, 256, 0, stream>>>(W3, W4, W5, Wt);
    k_w12<<<256, 256, 0, stream>>>(x, Wt, Wt + 16384, b3, b4, w1b, w2t, xt, diag);
    k_S<<<512, 256, 0, stream>>>(xt, w2t, St);
    k_out_w12<<<256, 256, 0, stream>>>(x, w1b, St, diag, Wt + 2 * 16384, b5, out,
                                       Wt + 3 * 16384, Wt + 4 * 16384,
                                       b3 + FF, b4 + FF, w1b, w2t, xt, diag);
    k_S<<<512, 256, 0, stream>>>(xt, w2t, St);
    k_out<<<256, 256, 0, stream>>>(out, w1b, St, diag, Wt + 5 * 16384, b5 + FF, out);
}

// Round 7
// 125.098 us; speedup vs baseline: 3.5854x; 1.0888x over previous
//
#include <hip/hip_runtime.h>

#define NN 2048
#define FF 128
#define SLOPE 0.1f
#define LS 136              // padded bf16 row stride in LDS

typedef __attribute__((ext_vector_type(8))) short short8;
typedef __attribute__((ext_vector_type(4))) float f32x4;

__device__ __forceinline__ float lrelu(float v) { return v >= 0.f ? v : SLOPE * v; }

__device__ __forceinline__ ushort f2bf(float f) {
    uint u = __float_as_uint(f);
    return (ushort)((u + 0x7fffu + ((u >> 16) & 1u)) >> 16);
}

// ---------------------------------------------------------------------------
// 32-row tile helpers
// ---------------------------------------------------------------------------

// acc[2][2] += A(32x128 LDS, stride LS) @ B^T (global [n][128] bf16)
__device__ __forceinline__ void mfma_AB(
    const ushort* __restrict__ As, const ushort* __restrict__ Bg,
    int c, int quad, int ct0, f32x4 acc[2][2])
{
#pragma unroll
    for (int kk = 0; kk < 4; kk++) {
        short8 a0 = *(const short8*)&As[c * LS + kk * 32 + quad * 8];
        short8 a1 = *(const short8*)&As[(16 + c) * LS + kk * 32 + quad * 8];
#pragma unroll
        for (int ct = 0; ct < 2; ct++) {
            const int n = (ct0 + ct) * 16 + c;
            short8 bf = *(const short8*)&Bg[n * 128 + kk * 32 + quad * 8];
            acc[0][ct] = __builtin_amdgcn_mfma_f32_16x16x32_bf16(a0, bf, acc[0][ct], 0, 0, 0);
            acc[1][ct] = __builtin_amdgcn_mfma_f32_16x16x32_bf16(a1, bf, acc[1][ct], 0, 0, 0);
        }
    }
}

// transposed coalesced write: dstb[g][jloc0+0..31] = s[j][g]; 32 B/thread
__device__ __forceinline__ void write_t32(
    const ushort* __restrict__ s, ushort* __restrict__ dstb,
    int jloc0, int tid)
{
    const int g = tid >> 1;
    const int h = tid & 1;
    uint p[8];
#pragma unroll
    for (int jj = 0; jj < 8; jj++) {
        const uint lo = s[(h * 16 + jj * 2) * LS + g];
        const uint hi = s[(h * 16 + jj * 2 + 1) * LS + g];
        p[jj] = lo | (hi << 16);
    }
    uint4* dst = (uint4*)&dstb[(size_t)g * NN + jloc0 + h * 16];
    dst[0] = make_uint4(p[0], p[1], p[2], p[3]);
    dst[1] = make_uint4(p[4], p[5], p[6], p[7]);
}

// linear coalesced copy LDS tile (stride LS) -> global row-major [32][128]
__device__ __forceinline__ void store_lin32(
    const ushort* __restrict__ s, ushort* __restrict__ g, int tid)
{
#pragma unroll
    for (int i = 0; i < 2; i++) {
        const int off = (i * 256 + tid) * 8;
        *(short8*)&g[off] = *(const short8*)&s[(off >> 7) * LS + (off & 127)];
    }
}

// linear coalesced copy global row-major [32][128] -> LDS tile (stride LS)
__device__ __forceinline__ void load_lin32(
    const ushort* __restrict__ g, ushort* __restrict__ s, int tid)
{
#pragma unroll
    for (int i = 0; i < 2; i++) {
        const int off = (i * 256 + tid) * 8;
        *(short8*)&s[(off >> 7) * LS + (off & 127)] = *(const short8*)&g[off];
    }
}

// twin-GEMM epilogue: lrelu+bias, w1/w2 -> LDS tiles, diag partials -> LDS
__device__ __forceinline__ void epi_w12(
    const f32x4 acc1[2][2], const f32x4 acc2[2][2],
    const float* __restrict__ b3, const float* __restrict__ b4,
    ushort* __restrict__ w1s, ushort* __restrict__ w2s, float* __restrict__ diag_s,
    int c, int quad, int ct0)
{
    float dpar[2][4];
#pragma unroll
    for (int rt = 0; rt < 2; rt++)
#pragma unroll
        for (int r = 0; r < 4; r++) dpar[rt][r] = 0.f;

#pragma unroll
    for (int rt = 0; rt < 2; rt++) {
#pragma unroll
        for (int ct = 0; ct < 2; ct++) {
            const int gcol = (ct0 + ct) * 16 + c;
            const float bb3 = b3[gcol], bb4 = b4[gcol];
#pragma unroll
            for (int r = 0; r < 4; r++) {
                const float v1 = lrelu(acc1[rt][ct][r] + bb3);
                const float v2 = lrelu(acc2[rt][ct][r] + bb4);
                const int lrow = rt * 16 + quad * 4 + r;
                w1s[lrow * LS + gcol] = f2bf(v1);
                w2s[lrow * LS + gcol] = f2bf(v2);
                dpar[rt][r] += v1 * v2;
            }
        }
    }
#pragma unroll
    for (int rt = 0; rt < 2; rt++) {
#pragma unroll
        for (int r = 0; r < 4; r++) {
            float dp = dpar[rt][r];
            dp += __shfl_xor(dp, 1, 64);
            dp += __shfl_xor(dp, 2, 64);
            dp += __shfl_xor(dp, 4, 64);
            dp += __shfl_xor(dp, 8, 64);
            if (c == 0) atomicAdd(&diag_s[rt * 16 + quad * 4 + r], dp);
        }
    }
}

// ---------------------------------------------------------------------------
// K0: bf16 weight transpose Wt[m][g][f] = W[m][f][g]
// ---------------------------------------------------------------------------
__global__ __launch_bounds__(256) void k_prep(
    const float* __restrict__ W3, const float* __restrict__ W4,
    const float* __restrict__ W5, ushort* __restrict__ Wt)
{
    const int idx = blockIdx.x * 256 + threadIdx.x;
    const int m = idx >> 14;
    const int rem = idx & 16383;
    const int f = rem & 127;
    const int g = rem >> 7;
    const int l = m / 3, w = m % 3;
    const float* src = (w == 0) ? W3 : (w == 1) ? W4 : W5;
    Wt[m * 16384 + g * 128 + f] = f2bf(src[l * 16384 + f * 128 + g]);
}

// ---------------------------------------------------------------------------
// K1: 512 blocks x 32 rows. w1b row-major, w2t+xt transposed (coalesced), diag.
// ---------------------------------------------------------------------------
__global__ __launch_bounds__(256, 2) void k_w12(
    const float* __restrict__ x, const ushort* __restrict__ w3t,
    const ushort* __restrict__ w4t, const float* __restrict__ b3,
    const float* __restrict__ b4, ushort* __restrict__ w1b,
    ushort* __restrict__ w2t, ushort* __restrict__ xt,
    float* __restrict__ diag)
{
    __shared__ ushort xs[32 * LS];
    __shared__ ushort w2s[32 * LS];
    __shared__ float diag_s[32];

    const int tid = threadIdx.x;
    const int row0 = blockIdx.x * 32;
    const int b = row0 >> 11;
    const int jloc0 = row0 & 2047;

    if (tid < 32) diag_s[tid] = 0.f;

    // stage x (fp32) -> bf16 LDS
    const float4* xg4 = (const float4*)(x + (size_t)row0 * FF);
#pragma unroll
    for (int i = 0; i < 4; i++) {
        const int f4 = i * 256 + tid;
        const int row = f4 >> 5;
        const int k = (f4 & 31) * 4;
        float4 v = xg4[f4];
        ushort4 h;
        h.x = f2bf(v.x); h.y = f2bf(v.y); h.z = f2bf(v.z); h.w = f2bf(v.w);
        *(ushort4*)&xs[row * LS + k] = h;
    }
    __syncthreads();

    write_t32(xs, xt + (size_t)b * (FF * NN), jloc0, tid);

    const int lane = tid & 63;
    const int wave = tid >> 6;
    const int c = lane & 15;
    const int quad = lane >> 4;
    const int ct0 = wave * 2;

    f32x4 a1[2][2], a2[2][2];
#pragma unroll
    for (int rt = 0; rt < 2; rt++)
#pragma unroll
        for (int ct = 0; ct < 2; ct++) { a1[rt][ct] = (f32x4)0.f; a2[rt][ct] = (f32x4)0.f; }
    mfma_AB(xs, w3t, c, quad, ct0, a1);
    mfma_AB(xs, w4t, c, quad, ct0, a2);

    __syncthreads();   // all xs reads done; reuse xs for the w1 tile
    epi_w12(a1, a2, b3, b4, xs, w2s, diag_s, c, quad, ct0);
    __syncthreads();

    store_lin32(xs, w1b + (size_t)row0 * FF, tid);
    write_t32(w2s, w2t + (size_t)b * (FF * NN), jloc0, tid);
    if (tid < 32) diag[row0 + tid] = diag_s[tid];
}

// ---------------------------------------------------------------------------
// K2: St[b][g][f] = bf16( sum_j xt[b][g][j]*w2t[b][f][j] ).  512 blocks (2/CU),
// one 16x16 tile per block, 4 waves split K=2048.
// ---------------------------------------------------------------------------
__global__ __launch_bounds__(256, 2) void k_S(
    const ushort* __restrict__ xt, const ushort* __restrict__ w2t,
    ushort* __restrict__ St)
{
    __shared__ float red[4][256];
    const int tid = threadIdx.x;
    const int lane = tid & 63;
    const int wave = tid >> 6;
    const int c = lane & 15;
    const int quad = lane >> 4;

    const int sb = blockIdx.x >> 6;        // batch
    const int gq = (blockIdx.x >> 3) & 7;  // 16-g group
    const int fs = blockIdx.x & 7;         // 16-f group

    const int j0 = wave * 512 + quad * 8;
    const ushort* ap = &xt[(size_t)sb * (FF * NN) + (size_t)(gq * 16 + c) * NN + j0];
    const ushort* bp = &w2t[(size_t)sb * (FF * NN) + (size_t)(fs * 16 + c) * NN + j0];

    f32x4 acc = (f32x4)0.f;
#pragma unroll
    for (int it = 0; it < 16; it++) {
        short8 a = *(const short8*)(ap + it * 32);
        short8 bv = *(const short8*)(bp + it * 32);
        acc = __builtin_amdgcn_mfma_f32_16x16x32_bf16(a, bv, acc, 0, 0, 0);
    }
#pragma unroll
    for (int r = 0; r < 4; r++) red[wave][(quad * 4 + r) * 16 + c] = acc[r];
    __syncthreads();

    const float s = red[0][tid] + red[1][tid] + red[2][tid] + red[3][tid];
    const int gl = tid >> 4, fl = tid & 15;
    St[(size_t)sb * (FF * FF) + (size_t)(gq * 16 + gl) * FF + fs * 16 + fl] = f2bf(s);
}

// ---------------------------------------------------------------------------
// K3: out = lrelu((w1@S - diag*x)/(N-1) @ W5 + b5) + x.  512 blocks x 32 rows.
// ---------------------------------------------------------------------------
__global__ __launch_bounds__(256, 2) void k_out(
    const float* __restrict__ xin, const ushort* __restrict__ w1b,
    const ushort* __restrict__ St, const float* __restrict__ diag,
    const ushort* __restrict__ w5t, const float* __restrict__ b5,
    float* __restrict__ out)
{
    __shared__ ushort sW[32 * LS];
    __shared__ ushort sT[32 * LS];

    const int tid = threadIdx.x;
    const int row0 = blockIdx.x * 32;
    const int b = row0 >> 11;
    const ushort* Sb = St + (size_t)b * (FF * FF);

    load_lin32(w1b + (size_t)row0 * FF, sW, tid);
    __syncthreads();

    const int lane = tid & 63;
    const int wave = tid >> 6;
    const int c = lane & 15;
    const int quad = lane >> 4;
    const int ct0 = wave * 2;

    f32x4 accm[2][2];
#pragma unroll
    for (int rt = 0; rt < 2; rt++)
#pragma unroll
        for (int ct = 0; ct < 2; ct++) accm[rt][ct] = (f32x4)0.f;
    mfma_AB(sW, Sb, c, quad, ct0, accm);

    const float inv = 1.f / (float)(NN - 1);
    float xsv[2][2][4];
#pragma unroll
    for (int rt = 0; rt < 2; rt++) {
        float dg[4];
#pragma unroll
        for (int r = 0; r < 4; r++) dg[r] = diag[row0 + rt * 16 + quad * 4 + r];
#pragma unroll
        for (int ct = 0; ct < 2; ct++) {
            const int gcol = (ct0 + ct) * 16 + c;
#pragma unroll
            for (int r = 0; r < 4; r++) {
                const int lrow = rt * 16 + quad * 4 + r;
                const float xv = xin[(size_t)(row0 + lrow) * FF + gcol];
                xsv[rt][ct][r] = xv;
                sT[lrow * LS + gcol] = f2bf((accm[rt][ct][r] - dg[r] * xv) * inv);
            }
        }
    }
    __syncthreads();

    f32x4 acc2[2][2];
#pragma unroll
    for (int rt = 0; rt < 2; rt++)
#pragma unroll
        for (int ct = 0; ct < 2; ct++) acc2[rt][ct] = (f32x4)0.f;
    mfma_AB(sT, w5t, c, quad, ct0, acc2);

#pragma unroll
    for (int rt = 0; rt < 2; rt++) {
#pragma unroll
        for (int ct = 0; ct < 2; ct++) {
            const int gcol = (ct0 + ct) * 16 + c;
            const float bb = b5[gcol];
#pragma unroll
            for (int r = 0; r < 4; r++) {
                const int lrow = rt * 16 + quad * 4 + r;
                out[(size_t)(row0 + lrow) * FF + gcol] =
                    lrelu(acc2[rt][ct][r] + bb) + xsv[rt][ct][r];
            }
        }
    }
}

// ---------------------------------------------------------------------------
// K4: fused out(layer l) + w12(layer l+1).  512 blocks x 32 rows.
// Per-block aliasing on w1b/diag is safe (reads precede writes, same rows).
// ---------------------------------------------------------------------------
__global__ __launch_bounds__(256, 2) void k_out_w12(
    const float* __restrict__ x, const ushort* __restrict__ w1b_in,
    const ushort* __restrict__ St, const float* __restrict__ diag_in,
    const ushort* __restrict__ w5t, const float* __restrict__ b5,
    float* __restrict__ out,
    const ushort* __restrict__ w3t, const ushort* __restrict__ w4t,
    const float* __restrict__ b3, const float* __restrict__ b4,
    ushort* __restrict__ w1b, ushort* __restrict__ w2t,
    ushort* __restrict__ xt, float* __restrict__ diag)
{
    __shared__ ushort sA[32 * LS];
    __shared__ ushort sB[32 * LS];
    __shared__ float diag_s[32];

    const int tid = threadIdx.x;
    const int row0 = blockIdx.x * 32;
    const int b = row0 >> 11;
    const int jloc0 = row0 & 2047;
    const ushort* Sb = St + (size_t)b * (FF * FF);

    if (tid < 32) diag_s[tid] = 0.f;

    load_lin32(w1b_in + (size_t)row0 * FF, sA, tid);
    __syncthreads();

    const int lane = tid & 63;
    const int wave = tid >> 6;
    const int c = lane & 15;
    const int quad = lane >> 4;
    const int ct0 = wave * 2;

    // ---- phase A: msg = (w1@S - diag*x)/(N-1) -> sB ----
    f32x4 accm[2][2];
#pragma unroll
    for (int rt = 0; rt < 2; rt++)
#pragma unroll
        for (int ct = 0; ct < 2; ct++) accm[rt][ct] = (f32x4)0.f;
    mfma_AB(sA, Sb, c, quad, ct0, accm);

    const float inv = 1.f / (float)(NN - 1);
    float xsv[2][2][4];
#pragma unroll
    for (int rt = 0; rt < 2; rt++) {
        float dg[4];
#pragma unroll
        for (int r = 0; r < 4; r++) dg[r] = diag_in[row0 + rt * 16 + quad * 4 + r];
#pragma unroll
        for (int ct = 0; ct < 2; ct++) {
            const int gcol = (ct0 + ct) * 16 + c;
#pragma unroll
            for (int r = 0; r < 4; r++) {
                const int lrow = rt * 16 + quad * 4 + r;
                const float xv = x[(size_t)(row0 + lrow) * FF + gcol];
                xsv[rt][ct][r] = xv;
                sB[lrow * LS + gcol] = f2bf((accm[rt][ct][r] - dg[r] * xv) * inv);
            }
        }
    }
    __syncthreads();   // sB = msg; all sA (w1) reads done

    // ---- phase B: out = lrelu(msg@W5 + b5) + x; out tile -> sA ----
    f32x4 acc2[2][2];
#pragma unroll
    for (int rt = 0; rt < 2; rt++)
#pragma unroll
        for (int ct = 0; ct < 2; ct++) acc2[rt][ct] = (f32x4)0.f;
    mfma_AB(sB, w5t, c, quad, ct0, acc2);

#pragma unroll
    for (int rt = 0; rt < 2; rt++) {
#pragma unroll
        for (int ct = 0; ct < 2; ct++) {
            const int gcol = (ct0 + ct) * 16 + c;
            const float bb = b5[gcol];
#pragma unroll
            for (int r = 0; r < 4; r++) {
                const int lrow = rt * 16 + quad * 4 + r;
                const float ov = lrelu(acc2[rt][ct][r] + bb) + xsv[rt][ct][r];
                out[(size_t)(row0 + lrow) * FF + gcol] = ov;
                sA[lrow * LS + gcol] = f2bf(ov);
            }
        }
    }
    __syncthreads();   // sA = out-bf16; all sB (msg) reads done

    // ---- phase C: next layer's w12 from the out tile ----
    write_t32(sA, xt + (size_t)b * (FF * NN), jloc0, tid);

    f32x4 a1[2][2], a2[2][2];
#pragma unroll
    for (int rt = 0; rt < 2; rt++)
#pragma unroll
        for (int ct = 0; ct < 2; ct++) { a1[rt][ct] = (f32x4)0.f; a2[rt][ct] = (f32x4)0.f; }
    mfma_AB(sA, w3t, c, quad, ct0, a1);
    mfma_AB(sA, w4t, c, quad, ct0, a2);

    __syncthreads();   // all sA reads done; sB free
    epi_w12(a1, a2, b3, b4, sB /*w1'*/, sA /*w2'*/, diag_s, c, quad, ct0);
    __syncthreads();

    store_lin32(sB, w1b + (size_t)row0 * FF, tid);
    write_t32(sA, w2t + (size_t)b * (FF * NN), jloc0, tid);
    if (tid < 32) diag[row0 + tid] = diag_s[tid];
}

// ---------------------------------------------------------------------------
extern "C" void kernel_launch(void* const* d_in, const int* in_sizes, int n_in,
                              void* d_out, int out_size, void* d_ws, size_t ws_size,
                              hipStream_t stream)
{
    const float* x  = (const float*)d_in[0];
    const float* W3 = (const float*)d_in[1];
    const float* b3 = (const float*)d_in[2];
    const float* W4 = (const float*)d_in[3];
    const float* b4 = (const float*)d_in[4];
    const float* W5 = (const float*)d_in[5];
    const float* b5 = (const float*)d_in[6];
    float* out = (float*)d_out;

    char* ws = (char*)d_ws;
    ushort* w1b  = (ushort*)(ws);                        // 4 MB bf16 [16384][128]
    ushort* w2t  = (ushort*)(ws + ((size_t)4  << 20));   // 4 MB bf16 [8][128][2048]
    ushort* xt   = (ushort*)(ws + ((size_t)8  << 20));   // 4 MB bf16 [8][128][2048]
    float*  diag = (float*) (ws + ((size_t)12 << 20));   // 64 KB fp32 [16384]
    ushort* St   = (ushort*)(ws + ((size_t)13 << 20));   // 256 KB bf16 [8][128][128]
    ushort* Wt   = (ushort*)(ws + ((size_t)13 << 20) + (512 << 10));  // 192 KB

    k_prep<<<384, 256, 0, stream>>>(W3, W4, W5, Wt);
    k_w12<<<512, 256, 0, stream>>>(x, Wt, Wt + 16384, b3, b4, w1b, w2t, xt, diag);
    k_S<<<512, 256, 0, stream>>>(xt, w2t, St);
    k_out_w12<<<512, 256, 0, stream>>>(x, w1b, St, diag, Wt + 2 * 16384, b5, out,
                                       Wt + 3 * 16384, Wt + 4 * 16384,
                                       b3 + FF, b4 + FF, w1b, w2t, xt, diag);
    k_S<<<512, 256, 0, stream>>>(xt, w2t, St);
    k_out<<<512, 256, 0, stream>>>(out, w1b, St, diag, Wt + 5 * 16384, b5 + FF, out);
}